// Round 10
// baseline (819.194 us; speedup 1.0000x reference)
//
#include <hip/hip_runtime.h>
#include <cstdint>
#include <cstddef>

#define U_CNT 100000
#define I_CNT 50000
#define D_DIM 64
#define N_CNT (U_CNT + I_CNT)
#define NNZ_CNT 4000000
#define EPS_F 0.2f

// ---- bucket-sort CSR build geometry (round-10: smoother grid shapes) ----
#define BROWS 256                                   // rows per bucket (bucket = row>>8)
#define NBUCK ((N_CNT + BROWS - 1) / BROWS)         // 586
#define BCAP  7424                                  // staged cap/bucket (mean 6827, sigma~83 -> 7+ sigma)
#define QUADS (NNZ_CNT / 4)                         // 1,000,000 int4-quads
#define QPB   2048                                  // quads per passA block (8192 edges)
#define GA    ((QUADS + QPB - 1) / QPB)             // 489 blocks (~2/CU)
#define COL_MASK 0x3FFFF                            // col < 150000 < 2^18

// ---------------- passA: partition edges into row-buckets ----------------
// Per block: (1) LDS histogram of its 8K-edge tile over 586 buckets,
// (2) ONE global atomicAdd per (block,bucket) reserves a contiguous run,
// (3) re-walk tile, append (rl<<18|col, val) into the run. Block footprint
// (~65KB) is L2-resident, so staged lines fill before writeback.
__global__ __launch_bounds__(512) void passA_kernel(
    const int* __restrict__ rows, const int* __restrict__ cols,
    const float* __restrict__ vals, int* __restrict__ gcur,
    int2* __restrict__ staged) {
    __shared__ int lcnt[NBUCK];
    __shared__ int goff[NBUCK];
    __shared__ int lcur[NBUCK];
    const int t = threadIdx.x;
    for (int i = t; i < NBUCK; i += 512) { lcnt[i] = 0; lcur[i] = 0; }
    __syncthreads();
    const int qbase = blockIdx.x * QPB;
    // phase 1: tile histogram
    #pragma unroll
    for (int k = 0; k < QPB / 512; ++k) {
        int q = qbase + t + k * 512;
        if (q < QUADS) {
            int4 r4 = ((const int4*)rows)[q];
            atomicAdd(&lcnt[r4.x >> 8], 1);
            atomicAdd(&lcnt[r4.y >> 8], 1);
            atomicAdd(&lcnt[r4.z >> 8], 1);
            atomicAdd(&lcnt[r4.w >> 8], 1);
        }
    }
    __syncthreads();
    // reserve per-bucket runs (~287K atomics total across the grid)
    for (int b = t; b < NBUCK; b += 512)
        goff[b] = (lcnt[b] > 0) ? atomicAdd(&gcur[b], lcnt[b]) : 0;
    __syncthreads();
    // phase 2: append into reserved runs
    #pragma unroll
    for (int k = 0; k < QPB / 512; ++k) {
        int q = qbase + t + k * 512;
        if (q < QUADS) {
            int4   r4 = ((const int4*)rows)[q];
            int4   c4 = ((const int4*)cols)[q];
            float4 v4 = ((const float4*)vals)[q];
            int b, p;
            b = r4.x >> 8; p = atomicAdd(&lcur[b], 1);
            staged[(size_t)b * BCAP + goff[b] + p] =
                make_int2(((r4.x & 255) << 18) | c4.x, __float_as_int(v4.x));
            b = r4.y >> 8; p = atomicAdd(&lcur[b], 1);
            staged[(size_t)b * BCAP + goff[b] + p] =
                make_int2(((r4.y & 255) << 18) | c4.y, __float_as_int(v4.y));
            b = r4.z >> 8; p = atomicAdd(&lcur[b], 1);
            staged[(size_t)b * BCAP + goff[b] + p] =
                make_int2(((r4.z & 255) << 18) | c4.z, __float_as_int(v4.z));
            b = r4.w >> 8; p = atomicAdd(&lcur[b], 1);
            staged[(size_t)b * BCAP + goff[b] + p] =
                make_int2(((r4.w & 255) << 18) | c4.w, __float_as_int(v4.w));
        }
    }
}

// ---------------- scanB: bucket sizes -> cpack bases (586 <= 1024) ----------
__global__ __launch_bounds__(1024) void scanB_kernel(
    const int* __restrict__ gcur, int* __restrict__ cbase,
    int* __restrict__ rowptr) {
    __shared__ int lds[1024];
    const int t = threadIdx.x;
    lds[t] = (t < NBUCK) ? gcur[t] : 0;
    __syncthreads();
    for (int off = 1; off < 1024; off <<= 1) {
        int x = (t >= off) ? lds[t - off] : 0;
        __syncthreads();
        lds[t] += x;
        __syncthreads();
    }
    if (t < NBUCK) cbase[t] = (t > 0) ? lds[t - 1] : 0;
    if (t == 0) rowptr[N_CNT] = NNZ_CNT;
}

// ---------------- passB: per-bucket rowptr + final cpack ----------------
// One block OWNS one bucket: its cpack slice (~55KB) is written only by this
// block -> lines live in one XCD's L2 and fill completely before writeback.
__global__ __launch_bounds__(512) void passB_kernel(
    const int2* __restrict__ staged, const int* __restrict__ gcur,
    const int* __restrict__ cbase, int* __restrict__ rowptr,
    int2* __restrict__ cpack) {
    __shared__ int cnt[BROWS];
    __shared__ int cur[BROWS];
    const int b = blockIdx.x;
    const int t = threadIdx.x;
    const int nE = gcur[b];
    const int base = cbase[b];
    const int row0 = b * BROWS;
    const int rowsIn = (N_CNT - row0 < BROWS) ? (N_CNT - row0) : BROWS;
    const int2* sb = staged + (size_t)b * BCAP;
    if (t < BROWS) cnt[t] = 0;
    __syncthreads();
    for (int e = t; e < nE; e += 512)
        atomicAdd(&cnt[((unsigned)sb[e].x) >> 18], 1);
    __syncthreads();
    // inclusive scan over BROWS row counts (threads t<BROWS participate)
    for (int off = 1; off < BROWS; off <<= 1) {
        int x = (t < BROWS && t >= off) ? cnt[t - off] : 0;
        __syncthreads();
        if (t < BROWS) cnt[t] += x;
        __syncthreads();
    }
    if (t < BROWS) {
        int excl = (t > 0) ? cnt[t - 1] : 0;
        cur[t] = excl;
        if (t < rowsIn) rowptr[row0 + t] = base + excl;
    }
    __syncthreads();
    for (int e = t; e < nE; e += 512) {
        int2 pk = sb[e];
        int rl = ((unsigned)pk.x) >> 18;
        int p = atomicAdd(&cur[rl], 1);
        cpack[base + p] = make_int2(pk.x & COL_MASK, pk.y);
    }
}

__device__ __forceinline__ float sgnf(float x) {
    return (x > 0.f) ? 1.f : ((x < 0.f) ? -1.f : 0.f);
}

// ---------------- fused SpMM + noise + accumulate (round-0 proven form) ------
// 16 lanes per row (each lane owns a float4 of D=64); 4 rows per wave,
// 16 rows per 256-thread block. Edge metadata read group-uniformly (no shfl).
// MODE 0: gather from (ue,ie) split; xnext = ego; acc_out = ego   (layer 0)
// MODE 1: gather from xin;          xnext = ego; acc_out += ego   (layer 1)
// MODE 2: gather from xin;          acc_out = (acc_out + ego)/3   (layer 2)
template <int MODE>
__global__ __launch_bounds__(256) void layer_kernel(
    const int* __restrict__ rowptr, const int2* __restrict__ cpack,
    const float4* __restrict__ xin, const float4* __restrict__ ue4,
    const float4* __restrict__ ie4,
    const float4* __restrict__ noise_k, float4* __restrict__ xnext,
    float4* __restrict__ acc_out) {
    const int gl = threadIdx.x & 15;                 // lane within 16-lane row group
    const int r  = blockIdx.x * 16 + (threadIdx.x >> 4);
    if (r >= N_CNT) return;
    const int start = rowptr[r];
    const int end   = rowptr[r + 1];

    float4 acc = make_float4(0.f, 0.f, 0.f, 0.f);
    #pragma unroll 4
    for (int e = start; e < end; ++e) {
        int2 p = cpack[e];                            // group-uniform 8B load
        float vj = __int_as_float(p.y);
        const float4* xb;
        if (MODE == 0) {
            xb = (p.x < U_CNT) ? (ue4 + (size_t)p.x * 16)
                               : (ie4 + (size_t)(p.x - U_CNT) * 16);
        } else {
            xb = xin + (size_t)p.x * 16;
        }
        float4 xr = xb[gl];                           // 256B/row, coalesced over 16 lanes
        acc.x += vj * xr.x;
        acc.y += vj * xr.y;
        acc.z += vj * xr.z;
        acc.w += vj * xr.w;
    }

    // normalized noise (norm over the row's 64 features = 16 lanes x 4 comps)
    float4 nz = noise_k[(size_t)r * 16 + gl];
    float sq = nz.x * nz.x + nz.y * nz.y + nz.z * nz.z + nz.w * nz.w;
    #pragma unroll
    for (int off = 8; off > 0; off >>= 1) sq += __shfl_xor(sq, off);
    float inv = EPS_F / fmaxf(sqrtf(sq), 1e-12f);

    float4 ego;
    ego.x = acc.x + sgnf(acc.x) * nz.x * inv;
    ego.y = acc.y + sgnf(acc.y) * nz.y * inv;
    ego.z = acc.z + sgnf(acc.z) * nz.z * inv;
    ego.w = acc.w + sgnf(acc.w) * nz.w * inv;

    size_t oi = (size_t)r * 16 + gl;
    if (MODE == 0) {
        xnext[oi] = ego;
        acc_out[oi] = ego;
    } else if (MODE == 1) {
        xnext[oi] = ego;
        float4 a = acc_out[oi];
        a.x += ego.x; a.y += ego.y; a.z += ego.z; a.w += ego.w;
        acc_out[oi] = a;
    } else {
        float4 a = acc_out[oi];
        a.x = (a.x + ego.x) * (1.f / 3.f);
        a.y = (a.y + ego.y) * (1.f / 3.f);
        a.z = (a.z + ego.z) * (1.f / 3.f);
        a.w = (a.w + ego.w) * (1.f / 3.f);
        acc_out[oi] = a;
    }
}

extern "C" void kernel_launch(void* const* d_in, const int* in_sizes, int n_in,
                              void* d_out, int out_size, void* d_ws, size_t ws_size,
                              hipStream_t stream) {
    const float* ue    = (const float*)d_in[0];
    const float* ie    = (const float*)d_in[1];
    const int*   rows  = (const int*)d_in[2];
    const int*   cols  = (const int*)d_in[3];
    const float* vals  = (const float*)d_in[4];
    const float* noise = (const float*)d_in[5];
    float* out = (float*)d_out;
    char*  ws  = (char*)d_ws;

    auto align16 = [](size_t x) { return (x + 15) & ~(size_t)15; };
    size_t off = 0;
    int*   rowptr = (int*)(ws + off);  off = align16(off + (size_t)(N_CNT + 1) * 4);
    int*   gcur   = (int*)(ws + off);  off = align16(off + (size_t)NBUCK * 4);
    int*   cbase  = (int*)(ws + off);  off = align16(off + (size_t)NBUCK * 4);
    int2*  cpack  = (int2*)(ws + off); off = align16(off + (size_t)NNZ_CNT * 8);
    float* bufA   = (float*)(ws + off); off += (size_t)N_CNT * D_DIM * 4;
    // staged (586*7424*8 = 34.8MB) aliases bufA (38.4MB): staged is dead
    // before layer 1 writes bufA.
    int2*  staged = (int2*)bufA;
    (void)ws_size; (void)in_sizes; (void)n_in; (void)out_size;

    const size_t ND = (size_t)N_CNT * D_DIM;
    float* cl = out + ND;  // ego_cl region; doubles as layer-0 output / layer-1 input

    // ---- CSR build: two-pass bucket sort ----
    hipMemsetAsync(gcur, 0, (size_t)NBUCK * 4, stream);
    passA_kernel<<<GA, 512, 0, stream>>>(rows, cols, vals, gcur, staged);
    scanB_kernel<<<1, 1024, 0, stream>>>(gcur, cbase, rowptr);
    passB_kernel<<<NBUCK, 512, 0, stream>>>(staged, gcur, cbase, rowptr, cpack);

    // ---- 3 propagation layers (round-0 proven form) ----
    int blocks = (N_CNT + 15) / 16;
    layer_kernel<0><<<blocks, 256, 0, stream>>>(rowptr, cpack, nullptr,
                                                (const float4*)ue, (const float4*)ie,
                                                (const float4*)(noise + 0 * ND),
                                                (float4*)cl, (float4*)out);
    layer_kernel<1><<<blocks, 256, 0, stream>>>(rowptr, cpack, (const float4*)cl,
                                                nullptr, nullptr,
                                                (const float4*)(noise + 1 * ND),
                                                (float4*)bufA, (float4*)out);
    layer_kernel<2><<<blocks, 256, 0, stream>>>(rowptr, cpack, (const float4*)bufA,
                                                nullptr, nullptr,
                                                (const float4*)(noise + 2 * ND),
                                                nullptr, (float4*)out);
}